// Round 2
// baseline (428.869 us; speedup 1.0000x reference)
//
#include <hip/hip_runtime.h>
#include <cstdint>
#include <cstddef>

#define NN    8192      // N
#define NIN   4096      // N_IN
#define BB    16        // B
#define BN    131072    // B*N
#define ROWCH 256       // rows per chunk -> grid 16x48 = 768 = 3 blocks/CU exactly
#define NCHI  32        // int chunks  (8192/256)
#define NCHE  16        // ext chunks  (4096/256)
#define NCH   48        // total chunks
#define LCAP  64        // per-batch active-row list capacity (Binom(256,0.05): mean 12.8, 64 = +14 sigma)

static constexpr float ALPHA_F = 0.9512294245007140f;               // fl32(exp(-0.05))
static constexpr float RHOA_F  = 0.9950124791926823f;               // fl32(exp(-0.005))
static constexpr float SCALE_F = (float)(1.0 - 0.9512294245007140); // fl32(1 - alpha)

// ---------------------------------------------------------------------------
// k_aux: (a) per-row spike bit-masks from Xd[-1] / Xext, (b) delay-buffer
// shift Xd_new[1:8] = Xd[0:7] (float4). Grid-stride over 7*BN/4 float4s.
// ---------------------------------------------------------------------------
__global__ __launch_bounds__(256) void k_aux(
    const float* __restrict__ Xd, const float* __restrict__ Xext,
    float* __restrict__ out,
    unsigned* __restrict__ mask_int, unsigned* __restrict__ mask_ext)
{
    const int t = blockIdx.x * 256 + threadIdx.x;   // [0, 7*BN/4)

    if (t < NN) {                       // internal mask from Xd[-1]
        unsigned m = 0;
        #pragma unroll
        for (int b = 0; b < BB; ++b)
            m |= (Xd[7*BN + b*NN + t] > 0.5f) ? (1u << b) : 0u;
        mask_int[t] = m;
    } else if (t < NN + NIN) {          // external mask from Xext
        const int i = t - NN;
        unsigned m = 0;
        #pragma unroll
        for (int b = 0; b < BB; ++b)
            m |= (Xext[b*NIN + i] > 0.5f) ? (1u << b) : 0u;
        mask_ext[i] = m;
    }

    // shift: Xd_new[1:8] = Xd[0:7]
    ((float4*)(out + (size_t)4*BN))[t] = ((const float4*)Xd)[t];
}

// ---------------------------------------------------------------------------
// k_mm: spike-driven sparse matmul.
// Key fact: P_SPIKE=0.05 -> an active row (any of 16 batch bits set, ~56% of
// rows) has only ~1.43 set bits on average. The old kernel did 16 b-iters x
// 2 FMAs per row (91% multiply-by-zero). Here we build PER-BATCH row lists
// in LDS during compaction, then run 16 compile-time passes, each a tight
// {uniform ds_read row-id -> global_load_dwordx2 -> 2 v_add} loop over that
// batch's ~13 rows. VALU per (row,batch) pair drops ~8x; k_mm becomes
// HBM-bound on the active W rows (~215 MB -> ~37 us floor).
// List order from LDS atomics is nondeterministic: float-add reordering only,
// same class as the chunked reduction (absmax 3.8e-6 << tolerance).
// ---------------------------------------------------------------------------
__global__ __launch_bounds__(256) void k_mm(
    const float* __restrict__ Wint, const float* __restrict__ Wext,
    const unsigned* __restrict__ mask_int, const unsigned* __restrict__ mask_ext,
    float* __restrict__ part)
{
    const int tid = threadIdx.x;
    const int y   = blockIdx.y;
    const bool is_int = (y < NCHI);
    const float*    W    = is_int ? Wint : Wext;
    const unsigned* mask = is_int ? mask_int : mask_ext;
    const int base_row   = (is_int ? y : (y - NCHI)) * ROWCH;

    __shared__ unsigned lst[BB][LCAP];
    __shared__ unsigned cnt[BB];

    if (tid < BB) cnt[tid] = 0u;
    __syncthreads();

    // build per-batch active-row lists (thread tid owns local row tid)
    unsigned m = mask[base_row + tid];
    while (m) {
        const int b = (int)__builtin_ctz(m);
        m &= m - 1u;
        const unsigned idx = atomicAdd(&cnt[b], 1u);
        lst[b][idx] = (unsigned)tid;
    }
    __syncthreads();

    const int n = (blockIdx.x << 9) + (tid << 1);   // 2 cols/thread, 512-col tile
    const float* Wb = W + (size_t)base_row * NN + n;

    float2 acc[BB];
    #pragma unroll
    for (int b = 0; b < BB; ++b) acc[b] = make_float2(0.f, 0.f);

    // 16 compile-time passes; acc[b] statically indexed (stays in VGPRs)
    #pragma unroll
    for (int b = 0; b < BB; ++b) {
        const int c = (int)cnt[b];
        int j = 0;
        for (; j + 4 <= c; j += 4) {
            const int r0 = (int)lst[b][j + 0];
            const int r1 = (int)lst[b][j + 1];
            const int r2 = (int)lst[b][j + 2];
            const int r3 = (int)lst[b][j + 3];
            const float2 w0 = *(const float2*)(Wb + (r0 << 13));
            const float2 w1 = *(const float2*)(Wb + (r1 << 13));
            const float2 w2 = *(const float2*)(Wb + (r2 << 13));
            const float2 w3 = *(const float2*)(Wb + (r3 << 13));
            acc[b].x += w0.x; acc[b].y += w0.y;
            acc[b].x += w1.x; acc[b].y += w1.y;
            acc[b].x += w2.x; acc[b].y += w2.y;
            acc[b].x += w3.x; acc[b].y += w3.y;
        }
        for (; j < c; ++j) {
            const int r = (int)lst[b][j];
            const float2 w = *(const float2*)(Wb + (r << 13));
            acc[b].x += w.x; acc[b].y += w.y;
        }
    }

    float* p = part + (size_t)y * BN + n;
    #pragma unroll
    for (int b = 0; b < BB; ++b)
        *(float2*)(p + (size_t)b * NN) = acc[b];
}

// ---------------------------------------------------------------------------
// k_fin: fused ALIF elementwise + partial reduction (48 partials).
// out layout: [X (BN) | V_new (BN) | a_new (BN) | Xd_new (8*BN)]
// 128-thread blocks -> 256 blocks so the reduction uses the whole chip.
// ---------------------------------------------------------------------------
__global__ __launch_bounds__(128) void k_fin(
    const float* __restrict__ V, const float* __restrict__ a,
    const float* __restrict__ part, float* __restrict__ out)
{
    const int t4 = blockIdx.x * 128 + threadIdx.x;  // [0, BN/4)

    float4 s = make_float4(0.f, 0.f, 0.f, 0.f);
    #pragma unroll 8
    for (int c = 0; c < NCH; ++c) {
        const float4 p = ((const float4*)(part + (size_t)c * BN))[t4];
        s.x += p.x; s.y += p.y; s.z += p.z; s.w += p.w;
    }

    const float4 v4 = ((const float4*)V)[t4];
    const float4 a4 = ((const float4*)a)[t4];
    float4 x4, vn4, an4;
    {
        const float* vv = &v4.x; const float* aa = &a4.x;
        float* xx = &x4.x; float* vn = &vn4.x; float* an = &an4.x;
        const float* ss = &s.x;
        #pragma unroll
        for (int k = 0; k < 4; ++k) {
            // exactness-critical: no FMA contraction on the threshold compare
            const float th = __fadd_rn(1.0f, __fmul_rn(1.8f, aa[k]));
            const bool spike = (vv[k] >= th);
            const float x = spike ? 1.0f : 0.0f;
            xx[k] = x;
            float v_new = spike ? 0.0f : __fmul_rn(ALPHA_F, vv[k]);
            vn[k] = __builtin_fmaf(SCALE_F, ss[k], v_new);
            an[k] = __fadd_rn(__fmul_rn(RHOA_F, aa[k]), x);
        }
    }
    ((float4*)out)[t4]                       = x4;   // X
    ((float4*)(out + (size_t)BN))[t4]        = vn4;  // V_new
    ((float4*)(out + (size_t)2*BN))[t4]      = an4;  // a_new
    ((float4*)(out + (size_t)3*BN))[t4]      = x4;   // Xd_new[0]
}

// ---------------------------------------------------------------------------
extern "C" void kernel_launch(void* const* d_in, const int* in_sizes, int n_in,
                              void* d_out, int out_size, void* d_ws, size_t ws_size,
                              hipStream_t stream)
{
    const float* V    = (const float*)d_in[0];
    const float* a    = (const float*)d_in[1];
    const float* Xd   = (const float*)d_in[2];
    const float* Xext = (const float*)d_in[3];
    const float* Wint = (const float*)d_in[4];
    const float* Wext = (const float*)d_in[5];
    float* out = (float*)d_out;

    unsigned* mask_int = (unsigned*)d_ws;                    // 8192 u32
    unsigned* mask_ext = mask_int + NN;                      // 4096 u32
    float*    part     = (float*)((char*)d_ws + 65536);      // NCH*BN f32 (25.2 MB)

    k_aux<<<(7*BN/4)/256, 256, 0, stream>>>(Xd, Xext, out, mask_int, mask_ext);
    k_mm<<<dim3(16, NCH), 256, 0, stream>>>(Wint, Wext, mask_int, mask_ext, part);
    k_fin<<<BN/4/128, 128, 0, stream>>>(V, a, part, out);
}